// Round 1
// baseline (1071.869 us; speedup 1.0000x reference)
//
#include <hip/hip_runtime.h>

// SAXS loss: soft-binned pair-distance histograms for pred & true structures,
// normalized, then L1-summed. N = 256*37 = 9472 atoms = 37 tiles of 256 exactly.
// Symmetry: compute i<j only (doubling cancels in normalization).

#define NATOMS  9472
#define TILE    256
#define NTILES  37                       // 9472 / 256, exact
#define TPAIRS  (NTILES * (NTILES + 1) / 2)  // 703 triangular tile pairs
#define NBINS   201
#define NREP    16                       // LDS histogram replicas
#define HSTRIDE 256                      // padded per-structure hist stride in ws

__global__ __launch_bounds__(TILE) void saxs_hist_kernel(
    const float* __restrict__ posPred,
    const float* __restrict__ posTrue,
    const float* __restrict__ mask,
    float* __restrict__ gh)
{
    const int t = threadIdx.x;
    const int s = blockIdx.y;                  // 0 = pred, 1 = true
    const float* __restrict__ pos = s ? posTrue : posPred;
    float* __restrict__ ghist = gh + s * HSTRIDE;

    // Decode triangular tile index -> (a, b) with a <= b. Wave-uniform, cheap.
    int p = blockIdx.x;
    int a = 0;
    while (p >= NTILES - a) { p -= NTILES - a; ++a; }
    const int b = a + p;

    __shared__ float4 sAtom[TILE];             // i-tile coords + mask
    __shared__ float  sHist[NREP * NBINS];     // 16 replicas; stride 201 (201%32=9,
                                               // gcd(9,32)=1 -> same bin in different
                                               // replicas hits different banks)

    for (int k = t; k < NREP * NBINS; k += TILE) sHist[k] = 0.0f;

    {
        const int ia = a * TILE + t;
        sAtom[t] = make_float4(pos[3 * ia], pos[3 * ia + 1], pos[3 * ia + 2], mask[ia]);
    }
    const int ja = b * TILE + t;
    const float xj = pos[3 * ja], yj = pos[3 * ja + 1], zj = pos[3 * ja + 2];
    const float mj = mask[ja];

    __syncthreads();

    float* __restrict__ rep = sHist + (t & (NREP - 1)) * NBINS;
    // Off-diagonal tile (a<b): every (i,j) already satisfies i_glob < j_glob.
    // Diagonal tile: thread t (j = base+t) takes i = 0..t-1 only.
    const int imax = (a == b) ? t : TILE;

    for (int i = 0; i < imax; ++i) {
        const float4 ai = sAtom[i];            // broadcast read, conflict-free
        const float dx = ai.x - xj;
        const float dy = ai.y - yj;
        const float dz = ai.z - zj;
        const float d2 = fmaf(dx, dx, fmaf(dy, dy, dz * dz));
        const float d  = sqrtf(fmaxf(d2, 1e-12f));
        // t = clip(d/0.5, 0, NBINS-1.000001); the fp32 upper bound is exactly 200.0f
        const float tt = fminf(d * 2.0f, 200.0f);
        const float fl = floorf(tt);
        const int   lo = (int)fl;
        const float frac = tt - fl;
        const float w  = ai.w * mj;
        const float wf = w * frac;
        const float wl = w - wf;               // w*(1-frac)
        const int   hi = lo < (NBINS - 1) ? lo + 1 : (NBINS - 1);
        atomicAdd(&rep[lo], wl);
        atomicAdd(&rep[hi], wf);
    }

    __syncthreads();

    // Reduce replicas, one global atomic per bin per block.
    for (int k = t; k < NBINS; k += TILE) {
        float acc = 0.0f;
        #pragma unroll
        for (int r = 0; r < NREP; ++r) acc += sHist[r * NBINS + k];
        atomicAdd(&ghist[k], acc);
    }
}

__global__ void saxs_loss_kernel(const float* __restrict__ gh, float* __restrict__ out)
{
    const int lane = threadIdx.x;              // single wave of 64
    float hp[4], ht[4];
    float sp = 0.0f, st = 0.0f;
    #pragma unroll
    for (int r = 0; r < 4; ++r) {
        const int k = lane + 64 * r;
        float a = 0.0f, c = 0.0f;
        if (k < NBINS) { a = gh[k]; c = gh[HSTRIDE + k]; }
        hp[r] = a; ht[r] = c;
        sp += a; st += c;
    }
    #pragma unroll
    for (int off = 32; off > 0; off >>= 1) {
        sp += __shfl_xor(sp, off);
        st += __shfl_xor(st, off);
    }
    sp += 1e-12f;
    st += 1e-12f;
    float l = 0.0f;
    #pragma unroll
    for (int r = 0; r < 4; ++r) l += fabsf(hp[r] / sp - ht[r] / st);
    #pragma unroll
    for (int off = 32; off > 0; off >>= 1) l += __shfl_xor(l, off);
    if (lane == 0) out[0] = l;
}

extern "C" void kernel_launch(void* const* d_in, const int* in_sizes, int n_in,
                              void* d_out, int out_size, void* d_ws, size_t ws_size,
                              hipStream_t stream)
{
    const float* pred = (const float*)d_in[0];  // final_atom_positions [256,37,3]
    const float* tru  = (const float*)d_in[1];  // all_atom_positions   [256,37,3]
    const float* msk  = (const float*)d_in[2];  // all_atom_mask        [256,37]
    float* out = (float*)d_out;
    float* ws  = (float*)d_ws;

    // ws is poisoned 0xAA before every timed launch — zero the histograms.
    hipMemsetAsync(d_ws, 0, 2 * HSTRIDE * sizeof(float), stream);

    dim3 grid(TPAIRS, 2);
    saxs_hist_kernel<<<grid, dim3(TILE), 0, stream>>>(pred, tru, msk, ws);
    saxs_loss_kernel<<<dim3(1), dim3(64), 0, stream>>>(ws, out);
}

// Round 2
// 1055.559 us; speedup vs baseline: 1.0155x; 1.0155x over previous
//
#include <hip/hip_runtime.h>

// SAXS loss: soft-binned pair-distance histograms for pred & true structures,
// normalized, then L1-summed. N = 256*37 = 9472 atoms = 37 tiles of 256 exactly.
// Symmetry: count i<j only (doubling cancels in normalization).
//
// R2: i-atoms staged in REGISTERS (one per lane) and broadcast via
// v_readlane (VALU) instead of LDS reads -> inner loop has zero lgkmcnt
// waits; only fire-and-forget ds_add_f32 atomics remain on the DS pipe.

#define NATOMS  9472
#define TILE    256
#define NTILES  37                            // 9472 / 256, exact
#define TPAIRS  (NTILES * (NTILES + 1) / 2)   // 703 triangular tile pairs
#define NBINS   201
#define NREP    16                            // LDS histogram replicas
#define HSTRIDE 256                           // per-structure hist stride in ws

__global__ __launch_bounds__(TILE) void saxs_hist_kernel(
    const float* __restrict__ posPred,
    const float* __restrict__ posTrue,
    const float* __restrict__ mask,
    float* __restrict__ gh)
{
    const int t    = threadIdx.x;
    const int lane = t & 63;
    const int s    = blockIdx.y;               // 0 = pred, 1 = true
    const float* __restrict__ pos = s ? posTrue : posPred;
    float* __restrict__ ghist = gh + s * HSTRIDE;

    // Decode triangular tile index -> (a, b), a <= b. Wave-uniform, once.
    int p = blockIdx.x;
    int a = 0;
    while (p >= NTILES - a) { p -= NTILES - a; ++a; }
    const int b = a + p;

    __shared__ float sHist[NREP * NBINS];      // stride 201: 201%32=9, gcd(9,32)=1
                                               // -> replicas of one bin spread banks

    for (int k = t; k < NREP * NBINS; k += TILE) sHist[k] = 0.0f;

    // j-atom (one per thread) from tile b.
    const int jg = b * TILE + t;
    const float xj = pos[3 * jg], yj = pos[3 * jg + 1], zj = pos[3 * jg + 2];
    const float mj = mask[jg];

    __syncthreads();

    float* __restrict__ rep = sHist + (t & (NREP - 1)) * NBINS;

    // i-tile (tile a, 256 atoms) in 4 chunks of 64: one atom per lane in
    // registers, broadcast with readlane (VALU pipe, no LDS).
    for (int c = 0; c < 4; ++c) {
        const int ia = a * TILE + c * 64 + lane;
        const int cx = __float_as_int(pos[3 * ia]);
        const int cy = __float_as_int(pos[3 * ia + 1]);
        const int cz = __float_as_int(pos[3 * ia + 2]);
        const int cm = __float_as_int(mask[ia]);

        #pragma unroll
        for (int i = 0; i < 64; ++i) {
            const float sx = __int_as_float(__builtin_amdgcn_readlane(cx, i));
            const float sy = __int_as_float(__builtin_amdgcn_readlane(cy, i));
            const float sz = __int_as_float(__builtin_amdgcn_readlane(cz, i));
            const float sm = __int_as_float(__builtin_amdgcn_readlane(cm, i));
            const int   ig = a * TILE + c * 64 + i;

            const float dx = sx - xj;
            const float dy = sy - yj;
            const float dz = sz - zj;
            const float d2 = fmaf(dx, dx, fmaf(dy, dy, dz * dz));
            const float d  = sqrtf(fmaxf(d2, 1e-12f));
            // clip(d/0.5, 0, NBINS-1.000001): fp32 upper bound is exactly 200.0f
            const float tt = fminf(d * 2.0f, 200.0f);
            const float fl = floorf(tt);
            const int   lo = (int)fl;
            const float frac = tt - fl;
            // i<j predicate folds diagonal masking + self-pair exclusion.
            const float w  = (ig < jg) ? sm * mj : 0.0f;
            const float wf = w * frac;
            const float wl = w - wf;           // w*(1-frac)
            const int   hi = lo < (NBINS - 1) ? lo + 1 : (NBINS - 1);
            atomicAdd(&rep[lo], wl);
            atomicAdd(&rep[hi], wf);
        }
    }

    __syncthreads();

    // Reduce replicas, one global atomic per bin per block.
    for (int k = t; k < NBINS; k += TILE) {
        float acc = 0.0f;
        #pragma unroll
        for (int r = 0; r < NREP; ++r) acc += sHist[r * NBINS + k];
        atomicAdd(&ghist[k], acc);
    }
}

__global__ void saxs_loss_kernel(const float* __restrict__ gh, float* __restrict__ out)
{
    const int lane = threadIdx.x;              // single wave of 64
    float hp[4], ht[4];
    float sp = 0.0f, st = 0.0f;
    #pragma unroll
    for (int r = 0; r < 4; ++r) {
        const int k = lane + 64 * r;
        float a = 0.0f, c = 0.0f;
        if (k < NBINS) { a = gh[k]; c = gh[HSTRIDE + k]; }
        hp[r] = a; ht[r] = c;
        sp += a; st += c;
    }
    #pragma unroll
    for (int off = 32; off > 0; off >>= 1) {
        sp += __shfl_xor(sp, off);
        st += __shfl_xor(st, off);
    }
    sp += 1e-12f;
    st += 1e-12f;
    float l = 0.0f;
    #pragma unroll
    for (int r = 0; r < 4; ++r) l += fabsf(hp[r] / sp - ht[r] / st);
    #pragma unroll
    for (int off = 32; off > 0; off >>= 1) l += __shfl_xor(l, off);
    if (lane == 0) out[0] = l;
}

extern "C" void kernel_launch(void* const* d_in, const int* in_sizes, int n_in,
                              void* d_out, int out_size, void* d_ws, size_t ws_size,
                              hipStream_t stream)
{
    const float* pred = (const float*)d_in[0];  // final_atom_positions [256,37,3]
    const float* tru  = (const float*)d_in[1];  // all_atom_positions   [256,37,3]
    const float* msk  = (const float*)d_in[2];  // all_atom_mask        [256,37]
    float* out = (float*)d_out;
    float* ws  = (float*)d_ws;

    // ws is poisoned 0xAA before every timed launch — zero the histograms.
    hipMemsetAsync(d_ws, 0, 2 * HSTRIDE * sizeof(float), stream);

    dim3 grid(TPAIRS, 2);
    saxs_hist_kernel<<<grid, dim3(TILE), 0, stream>>>(pred, tru, msk, ws);
    saxs_loss_kernel<<<dim3(1), dim3(64), 0, stream>>>(ws, out);
}